// Round 5
// baseline (12.599 us; speedup 1.0000x reference)
//
#include <hip/hip_runtime.h>

// CenterLoss: B=1024, D=128, C=100000.
// Exact algebraic collapse of the reference:
//   out = (1/B) * sum_b clip(||x_b - centers[labels_b]||^2, 1e-12, 1e12)
//         + (C-1) * 1e-12            // B*(C-1) masked zeros, each clamped to 1e-12
// ONE kernel dispatch. 256 blocks x 256 threads = 1024 waves, ONE sample per
// wave -> every gather load in flight at once (latency-min critical path).
// Cross-block completion via load-time-zeroed __device__ counter
// (poison-immune; last block resets it -> invariant across calls).

#define CL_B 1024
#define CL_D 128
#define CL_C 100000
#define NBLK 256                        // blocks; 4 samples per block (1/wave)

__device__ unsigned int cl_counter = 0;   // 0 at every call start & end
__device__ float        cl_partials[NBLK];

__global__ __launch_bounds__(256) void cl_onekernel(
    const float* __restrict__ x,
    const int* __restrict__ labels,
    const float* __restrict__ centers,
    float* __restrict__ out) {
    const int t    = threadIdx.x;       // 0..255
    const int wave = t >> 6;            // 0..3
    const int lane = t & 63;            // wave = 64 lanes on CDNA
    const int b    = (blockIdx.x << 2) + wave;   // sample id, 256*4 = 1024

    // One sample per wave: lane covers 2 floats (float2) of the 128-dim row.
    const int lab = labels[b];
    const float2 xv = reinterpret_cast<const float2*>(x + (size_t)b * CL_D)[lane];
    const float2 cv = reinterpret_cast<const float2*>(centers + (size_t)lab * CL_D)[lane];
    const float d0 = xv.x - cv.x;
    const float d1 = xv.y - cv.y;
    float s = d0 * d0 + d1 * d1;

    #pragma unroll
    for (int off = 32; off > 0; off >>= 1)
        s += __shfl_down(s, off, 64);

    __shared__ float sm[4];
    __shared__ int   is_last;
    if (lane == 0)
        sm[wave] = fminf(fmaxf(s, 1e-12f), 1e12f);   // clip per sample
    __syncthreads();

    if (t == 0) {
        cl_partials[blockIdx.x] = sm[0] + sm[1] + sm[2] + sm[3];
        __threadfence();                        // release partial (device scope)
        const unsigned old = atomicAdd(&cl_counter, 1u);
        is_last = (old == NBLK - 1u);
        if (is_last) {
            __threadfence();                    // acquire side
            atomicExch(&cl_counter, 0u);        // last arrival: safe reset
        }
    }
    __syncthreads();

    if (is_last) {
        // Last block: all 256 threads read one partial each; fixed-order
        // wave reduce + 4-way combine -> bitwise-deterministic.
        volatile const float* vp = cl_partials; // other blocks' writes
        float v = vp[t];
        #pragma unroll
        for (int off = 32; off > 0; off >>= 1)
            v += __shfl_down(v, off, 64);
        if (lane == 0) sm[wave] = v;
        __syncthreads();
        if (t == 0)
            out[0] = (sm[0] + sm[1] + sm[2] + sm[3]) / (float)CL_B
                     + (float)(CL_C - 1) * 1e-12f;
    }
}

extern "C" void kernel_launch(void* const* d_in, const int* in_sizes, int n_in,
                              void* d_out, int out_size, void* d_ws, size_t ws_size,
                              hipStream_t stream) {
    const float* x       = (const float*)d_in[0];   // [1024, 128] f32
    const int*   labels  = (const int*)d_in[1];     // [1024] int
    const float* centers = (const float*)d_in[2];   // [100000, 128] f32
    float* out = (float*)d_out;                     // [1] f32
    (void)d_ws; (void)ws_size;

    cl_onekernel<<<NBLK, 256, 0, stream>>>(x, labels, centers, out);
}